// Round 11
// baseline (454.336 us; speedup 1.0000x reference)
//
#include <hip/hip_runtime.h>
#include <hip/hip_bf16.h>
#include <stdint.h>

typedef __hip_bfloat16 bf16s;                                    // storage type
typedef __bf16 bf16x8 __attribute__((ext_vector_type(8)));       // MFMA operand
typedef float  floatx4 __attribute__((ext_vector_type(4)));      // MFMA acc

#define BM 256
#define BN 256
#define BK 64

__device__ __forceinline__ void gload_lds16(const void* g, void* l) {
    auto* gp = reinterpret_cast<const __attribute__((address_space(1))) uint32_t*>(
        reinterpret_cast<uintptr_t>(g));
    auto* lp = reinterpret_cast<__attribute__((address_space(3))) uint32_t*>(
        reinterpret_cast<uintptr_t>(l));
    __builtin_amdgcn_global_load_lds(gp, lp, 16, 0, 0);
}

// ---------- x (f32) -> bf16, vectorized ----------
__global__ void cvt_f32_bf16(const float* __restrict__ x, bf16s* __restrict__ y, long n4) {
    long i = (long)blockIdx.x * blockDim.x + threadIdx.x;
    long stride = (long)gridDim.x * blockDim.x;
    for (; i < n4; i += stride) {
        float4 v = ((const float4*)x)[i];
        bf16s tmp[4];
        tmp[0] = __float2bfloat16(v.x);
        tmp[1] = __float2bfloat16(v.y);
        tmp[2] = __float2bfloat16(v.z);
        tmp[3] = __float2bfloat16(v.w);
        *(uint2*)&y[i * 4] = *(uint2*)tmp;
    }
}

// ---------- Wadj = W + lora_B @ lora_A, output bf16 ----------
__global__ void adjust_weight(const float* __restrict__ W, const float* __restrict__ lA,
                              const float* __restrict__ lB, bf16s* __restrict__ Wb,
                              int N, int Kd, int r) {
    long idx = (long)blockIdx.x * blockDim.x + threadIdx.x;
    int kq = Kd >> 2;
    long total = (long)N * kq;
    if (idx >= total) return;
    int n  = (int)(idx / kq);
    int k4 = (int)(idx - (long)n * kq) << 2;
    float4 w = *(const float4*)&W[(size_t)n * Kd + k4];
    float a0 = w.x, a1 = w.y, a2 = w.z, a3 = w.w;
    for (int j = 0; j < r; ++j) {
        float b = lB[n * r + j];
        float4 av = *(const float4*)&lA[(size_t)j * Kd + k4];
        a0 += b * av.x; a1 += b * av.y; a2 += b * av.z; a3 += b * av.w;
    }
    bf16s tmp[4];
    tmp[0] = __float2bfloat16(a0);
    tmp[1] = __float2bfloat16(a1);
    tmp[2] = __float2bfloat16(a2);
    tmp[3] = __float2bfloat16(a3);
    *(uint2*)&Wb[(size_t)n * Kd + k4] = *(uint2*)tmp;
}

// ==========================================================================
// 256x256 tile, BK=64, 8 waves (2M x 4N), 16x16x32 MFMA.
// STRUCTURAL CHANGE vs r4-r10 (all LDS-port + matrix-pipe summed ≈46%):
// B operand NEVER touches LDS — each wave loads its 8 B-fragments per K-tile
// straight global->VGPR (B panel 32KB/K-tile is L2-hot; 64KB/CU/K-tile rides
// the otherwise-idle L2/TA pipe). LDS demand drops to A-only:
// 128 b128 reads (~1536cy) + 16KB DMA (~256cy) < MFMA floor (2484cy).
// B double-buffered in registers (bU/bV, static ping-pong via unrolled
// even/odd bodies); A-frags single-set (mh0 cluster then mh1 cluster) to fit
// VGPR ~130 + 128 AGPR at 2 waves/SIMD.
// Per tile: issue B(t+1) loads + A(t+1) DMA first (~2500cy slack vs ~400cy
// L2 latency), read A frags, 64 MFMA, vmcnt(0)+barrier (r7 ledger: RAW via
// boundary, WAR via previous boundary).
// A staging/swizzle verbatim r4 (verified, 0 bank conflicts):
// LDS slot s of row l holds source granule s^(l&7); A rows wm-major.
// ==========================================================================
__global__ __launch_bounds__(512, 2)
void gemm_breg(const bf16s* __restrict__ A,   // [M,K] bf16
               const bf16s* __restrict__ B,   // [N,K] bf16
               const float* __restrict__ bias,
               float* __restrict__ C,         // [M,N] f32
               int M, int N, int K) {
    __shared__ __align__(16) bf16s lds[2][BM * BK];   // A only: 2 x 32 KiB

    const int nbn = N / BN;
    const int nwg = gridDim.x;
    int bid = blockIdx.x;
    int swz = bid;
    if ((nwg & 7) == 0) swz = (bid & 7) * (nwg >> 3) + (bid >> 3);   // XCD swizzle
    const int bm = swz / nbn, bn = swz % nbn;

    const int th   = threadIdx.x;
    const int lane = th & 63;
    const int wid  = th >> 6;
    const int wm = wid >> 2;           // 0..1 -> 128-row slice
    const int wn = wid & 3;            // 0..3 -> 64-col slice
    const int lr = lane & 15;
    const int kg = lane >> 4;          // 16B granule group along K

    const bf16s* gA = A + (size_t)(bm * BM) * K;
    const bf16s* gBw = B + (size_t)(bn * BN + wn * 64 + lr) * K;   // wave's B rows
    const int NT = K / BK;             // 64

    floatx4 acc[8][4];
#pragma unroll
    for (int m = 0; m < 8; ++m)
#pragma unroll
        for (int n = 0; n < 4; ++n)
            acc[m][n] = (floatx4){0.f, 0.f, 0.f, 0.f};

    const int trow = th >> 3;                       // 0..63 rows per G-load
    const int tgr  = (th & 7) ^ (trow & 7);         // pre-swizzled src granule

    // A staging (verbatim r4): LDS row l = mh*128 + g*64 + q <-> phys row
    // p = g*128 + mh*64 + q; slot s holds source granule s^(l&7).
    auto stageA = [&](int dbuf, int mh, int k0) {
#pragma unroll
        for (int g = 0; g < 2; ++g) {
            int p = g * 128 + mh * 64 + trow;       // phys A row
            gload_lds16(gA + (size_t)p * K + k0 + tgr * 8,
                        &lds[dbuf][(mh * 128 + g * 64) * BK + th * 8]);
        }
    };

    auto ldA = [&](const bf16s* base, int mh, int mp, int kk) -> bf16x8 {
        int l = mh * 128 + wm * 64 + mp * 16 + lr;
        int c = ((kk << 2) | kg) ^ (lr & 7);
        return *(const bf16x8*)(base + l * BK + c * 8);
    };

    // B fragments straight from global: row = gBw + np*16 rows, k = kt+kk*32+kg*8
    auto loadB = [&](bf16x8 (&dst)[4][2], int kt) {
#pragma unroll
        for (int np = 0; np < 4; ++np)
#pragma unroll
            for (int kk = 0; kk < 2; ++kk)
                dst[np][kk] = *(const bf16x8*)(gBw + (size_t)(np * 16) * K + kt + kk * 32 + kg * 8);
    };

    bf16x8 bU[4][2], bV[4][2], af[4][2];

    // one K-tile body: prefetch (B-regs + A-DMA) for tile `tn`, compute tile
    // from `Abuf` x `bc`, then boundary.
#define TILE_BODY(Abuf, bc, bnext, kn)                                         \
    {                                                                          \
        loadB(bnext, (kn));                                                    \
        stageA((Abuf) ^ 1, 0, (kn));                                           \
        stageA((Abuf) ^ 1, 1, (kn));                                           \
        const bf16s* Ab_ = &lds[(Abuf)][0];                                    \
        _Pragma("unroll")                                                      \
        for (int mp = 0; mp < 4; ++mp)                                         \
            _Pragma("unroll")                                                  \
            for (int kk = 0; kk < 2; ++kk)                                     \
                af[mp][kk] = ldA(Ab_, 0, mp, kk);                              \
        __builtin_amdgcn_s_setprio(1);                                         \
        _Pragma("unroll")                                                      \
        for (int mp = 0; mp < 4; ++mp)                                         \
            _Pragma("unroll")                                                  \
            for (int np = 0; np < 4; ++np)                                     \
                _Pragma("unroll")                                              \
                for (int kk = 0; kk < 2; ++kk)                                 \
                    acc[mp][np] = __builtin_amdgcn_mfma_f32_16x16x32_bf16(     \
                        af[mp][kk], bc[np][kk], acc[mp][np], 0, 0, 0);         \
        __builtin_amdgcn_s_setprio(0);                                         \
        _Pragma("unroll")                                                      \
        for (int mp = 0; mp < 4; ++mp)                                         \
            _Pragma("unroll")                                                  \
            for (int kk = 0; kk < 2; ++kk)                                     \
                af[mp][kk] = ldA(Ab_, 1, mp, kk);                              \
        __builtin_amdgcn_s_setprio(1);                                         \
        _Pragma("unroll")                                                      \
        for (int mp = 0; mp < 4; ++mp)                                         \
            _Pragma("unroll")                                                  \
            for (int np = 0; np < 4; ++np)                                     \
                _Pragma("unroll")                                              \
                for (int kk = 0; kk < 2; ++kk)                                 \
                    acc[4 + mp][np] = __builtin_amdgcn_mfma_f32_16x16x32_bf16( \
                        af[mp][kk], bc[np][kk], acc[4 + mp][np], 0, 0, 0);     \
        __builtin_amdgcn_s_setprio(0);                                         \
        asm volatile("s_waitcnt vmcnt(0)" ::: "memory");                       \
        asm volatile("s_barrier" ::: "memory");                                \
    }

    // prologue: stage A(0) -> buf0, load B(0) -> bU, publish
    stageA(0, 0, 0);
    stageA(0, 1, 0);
    loadB(bU, 0);
    asm volatile("s_waitcnt vmcnt(0)" ::: "memory");
    asm volatile("s_barrier" ::: "memory");

    for (int it = 0; it < NT / 2; ++it) {
        const int u = 2 * it;
        const int kv  = (u + 1) * BK;
        const int ku2 = ((u + 2) < NT ? (u + 2) : (NT - 1)) * BK;   // clamped tail
        TILE_BODY(0, bU, bV, kv);    // tile u   (A buf0), prefetch v
        TILE_BODY(1, bV, bU, ku2);   // tile u+1 (A buf1), prefetch u+2
    }
#undef TILE_BODY

    // epilogue: C/D layout col = lane&15, row = (lane>>4)*4 + q
    const int crow = bm * BM + wm * 128;
    const int ccol = bn * BN + wn * 64;
#pragma unroll
    for (int n = 0; n < 4; ++n) {
        int col = ccol + n * 16 + lr;
        float bv = bias[col];
#pragma unroll
        for (int m = 0; m < 8; ++m) {
            int row0 = crow + m * 16 + kg * 4;
#pragma unroll
            for (int q = 0; q < 4; ++q)
                C[(size_t)(row0 + q) * N + col] = acc[m][n][q] + bv;
        }
    }
}

// ---------- fallback (f32, slow but correct) ----------
__global__ void xa_kernel(const float* __restrict__ x, const float* __restrict__ lA,
                          float* __restrict__ xa, long M, int K, int r) {
    long idx = (long)blockIdx.x * blockDim.x + threadIdx.x;
    long total = M * r;
    if (idx >= total) return;
    long m = idx / r; int j = (int)(idx % r);
    const float* xr = x + m * (long)K;
    const float* ar = lA + (size_t)j * K;
    float s = 0.f;
    for (int k = 0; k < K; k += 4) {
        float4 xv = *(const float4*)&xr[k];
        float4 av = *(const float4*)&ar[k];
        s += xv.x * av.x + xv.y * av.y + xv.z * av.z + xv.w * av.w;
    }
    xa[idx] = s;
}

__global__ void naive_out(const float* __restrict__ x, const float* __restrict__ W,
                          const float* __restrict__ bias, const float* __restrict__ xa,
                          const float* __restrict__ lB, float* __restrict__ out,
                          long M, int N, int K, int r) {
    long idx = (long)blockIdx.x * blockDim.x + threadIdx.x;
    long total = M * (long)N;
    if (idx >= total) return;
    long m = idx / N; int n = (int)(idx % N);
    const float* xr = x + m * (long)K;
    const float* wr = W + (size_t)n * K;
    float s = bias[n];
    for (int k = 0; k < K; k += 4) {
        float4 xv = *(const float4*)&xr[k];
        float4 wv = *(const float4*)&wr[k];
        s += xv.x * wv.x + xv.y * wv.y + xv.z * wv.z + xv.w * wv.w;
    }
    const float* xar = xa + m * r;
    const float* br  = lB + (size_t)n * r;
    for (int j = 0; j < r; ++j) s += xar[j] * br[j];
    out[idx] = s;
}

extern "C" void kernel_launch(void* const* d_in, const int* in_sizes, int n_in,
                              void* d_out, int out_size, void* d_ws, size_t ws_size,
                              hipStream_t stream) {
    const float* x    = (const float*)d_in[0];
    const float* W    = (const float*)d_in[1];
    const float* bias = (const float*)d_in[2];
    const float* lA   = (const float*)d_in[3];
    const float* lB   = (const float*)d_in[4];
    float* out = (float*)d_out;

    const int  N  = in_sizes[2];                  // d_out = 4096
    const int  Kd = in_sizes[1] / N;              // d_in  = 4096
    const int  r  = in_sizes[4] / N;              // 16
    const long M  = (long)in_sizes[0] / Kd;       // B*S   = 8192

    size_t xb_bytes = (size_t)M * Kd * sizeof(bf16s);
    size_t wb_bytes = (size_t)N * Kd * sizeof(bf16s);

    const int NTv = Kd / BK;
    if (ws_size >= xb_bytes + wb_bytes &&
        (M % BM) == 0 && (N % BN) == 0 && (Kd % BK) == 0 &&
        NTv >= 2 && (NTv % 2) == 0) {
        bf16s* xb = (bf16s*)d_ws;
        bf16s* wb = (bf16s*)((char*)d_ws + xb_bytes);

        long n4 = (long)M * Kd / 4;
        cvt_f32_bf16<<<2048, 256, 0, stream>>>(x, xb, n4);

        long total_w = (long)N * (Kd / 4);
        int blk_w = (int)((total_w + 255) / 256);
        adjust_weight<<<blk_w, 256, 0, stream>>>(W, lA, lB, wb, N, Kd, r);

        int grid = (int)(M / BM) * (N / BN);
        gemm_breg<<<grid, 512, 0, stream>>>(xb, wb, bias, out, (int)M, N, Kd);
    } else {
        // f32 fallback: xa = x @ lA^T  (M x r), then naive out
        float* xa = (float*)d_ws;   // needs M*r*4 bytes = 512 KB
        long total_xa = M * (long)r;
        int blk_xa = (int)((total_xa + 255) / 256);
        xa_kernel<<<blk_xa, 256, 0, stream>>>(x, lA, xa, M, Kd, r);
        long total_o = M * (long)N;
        int blk_o = (int)((total_o + 255) / 256);
        naive_out<<<blk_o, 256, 0, stream>>>(x, W, bias, xa, lB, out, M, N, Kd, r);
    }
}

// Round 12
// 314.841 us; speedup vs baseline: 1.4431x; 1.4431x over previous
//
#include <hip/hip_runtime.h>
#include <hip/hip_bf16.h>
#include <stdint.h>

typedef __hip_bfloat16 bf16s;                                    // storage type
typedef __bf16 bf16x8 __attribute__((ext_vector_type(8)));       // MFMA operand
typedef float  floatx4 __attribute__((ext_vector_type(4)));      // MFMA acc

#define BM 256
#define BN 256
#define BK 64

__device__ __forceinline__ void gload_lds16(const void* g, void* l) {
    auto* gp = reinterpret_cast<const __attribute__((address_space(1))) uint32_t*>(
        reinterpret_cast<uintptr_t>(g));
    auto* lp = reinterpret_cast<__attribute__((address_space(3))) uint32_t*>(
        reinterpret_cast<uintptr_t>(l));
    __builtin_amdgcn_global_load_lds(gp, lp, 16, 0, 0);
}

// ---------- fused: x (f32)->bf16  +  Wadj = W + lora_B@lora_A -> bf16 ----------
// blocks [0, XBLK): grid-stride convert of x; blocks [XBLK, ...): W chunks.
#define XBLK 2048
__global__ void prep_fused(const float* __restrict__ x, bf16s* __restrict__ xb, long n4,
                           const float* __restrict__ W, const float* __restrict__ lA,
                           const float* __restrict__ lB, bf16s* __restrict__ wb,
                           int N, int Kd, int r) {
    if (blockIdx.x < XBLK) {
        long i = (long)blockIdx.x * blockDim.x + threadIdx.x;
        long stride = (long)XBLK * blockDim.x;
        for (; i < n4; i += stride) {
            float4 v = ((const float4*)x)[i];
            bf16s tmp[4];
            tmp[0] = __float2bfloat16(v.x);
            tmp[1] = __float2bfloat16(v.y);
            tmp[2] = __float2bfloat16(v.z);
            tmp[3] = __float2bfloat16(v.w);
            *(uint2*)&xb[i * 4] = *(uint2*)tmp;
        }
    } else {
        long idx = (long)(blockIdx.x - XBLK) * blockDim.x + threadIdx.x;
        int kq = Kd >> 2;
        long total = (long)N * kq;
        if (idx >= total) return;
        int n  = (int)(idx / kq);
        int k4 = (int)(idx - (long)n * kq) << 2;
        float4 w = *(const float4*)&W[(size_t)n * Kd + k4];
        float a0 = w.x, a1 = w.y, a2 = w.z, a3 = w.w;
        for (int j = 0; j < r; ++j) {
            float b = lB[n * r + j];
            float4 av = *(const float4*)&lA[(size_t)j * Kd + k4];
            a0 += b * av.x; a1 += b * av.y; a2 += b * av.z; a3 += b * av.w;
        }
        bf16s tmp[4];
        tmp[0] = __float2bfloat16(a0);
        tmp[1] = __float2bfloat16(a1);
        tmp[2] = __float2bfloat16(a2);
        tmp[3] = __float2bfloat16(a3);
        *(uint2*)&wb[(size_t)n * Kd + k4] = *(uint2*)tmp;
    }
}

// ==========================================================================
// r9 schedule (m201 cadence: 8 phases / 2 K-tiles, vmcnt(6) at ph4/ph8,
// lgkmcnt(8) throttle on 12-read phases) with TEMPLATE-EXACT FENCING:
//   - __builtin_amdgcn_s_barrier() intrinsic (NO asm "memory" clobber)
//   - bare `s_waitcnt lgkmcnt(0)` + sched_barrier(0) after pre-MFMA barrier
//   - "memory" clobber retained ONLY on the two vmcnt(6) publication waits
// Hypothesis under test: 16 full compiler fences per iteration were blocking
// cross-phase scheduling (addr remat, stage/read stream motion) and causing
// the measured no-overlap (MfmaUtil pinned 46% across r4/r5/r7/r9).
// Staging/swizzle/ledger byte-identical to r9 (verified correct, 0 bank
// conflicts): LDS slot s of row l holds source granule s^(l&7).
// ==========================================================================
__global__ __launch_bounds__(512, 2)
void gemm_m201f(const bf16s* __restrict__ A,   // [M,K] bf16
                const bf16s* __restrict__ B,   // [N,K] bf16
                const float* __restrict__ bias,
                float* __restrict__ C,         // [M,N] f32
                int M, int N, int K) {
    __shared__ __align__(16) bf16s lds[2][2][BM * BK];   // [dbuf][A=0/B=1] 128 KiB

    const int nbn = N / BN;
    const int nwg = gridDim.x;
    int bid = blockIdx.x;
    int swz = bid;
    if ((nwg & 7) == 0) swz = (bid & 7) * (nwg >> 3) + (bid >> 3);   // XCD swizzle
    const int bm = swz / nbn, bn = swz % nbn;

    const int th   = threadIdx.x;
    const int lane = th & 63;
    const int wid  = th >> 6;
    const int wm = wid >> 2;           // 0..1 -> 128-row slice
    const int wn = wid & 3;            // 0..3 -> 64-col slice
    const int lr = lane & 15;
    const int kg = lane >> 4;          // 16B granule group along K

    const bf16s* gA = A + (size_t)(bm * BM) * K;
    const bf16s* gB = B + (size_t)(bn * BN) * K;
    const int NT  = K / BK;            // 64
    const int NIT = NT / 2;            // 32

    floatx4 acc[8][4];
#pragma unroll
    for (int m = 0; m < 8; ++m)
#pragma unroll
        for (int n = 0; n < 4; ++n)
            acc[m][n] = (floatx4){0.f, 0.f, 0.f, 0.f};

    const int trow = th >> 3;                       // 0..63 rows per G-load
    const int tgr  = (th & 7) ^ (trow & 7);         // pre-swizzled src granule

    auto stageA = [&](int dbuf, int mh, int k0) {
#pragma unroll
        for (int g = 0; g < 2; ++g) {
            int p = g * 128 + mh * 64 + trow;       // phys A row
            gload_lds16(gA + (size_t)p * K + k0 + tgr * 8,
                        &lds[dbuf][0][(mh * 128 + g * 64) * BK + th * 8]);
        }
    };
    auto stageB = [&](int dbuf, int nh, int k0) {
#pragma unroll
        for (int g = 0; g < 2; ++g) {
            int rest = g * 64 + trow;               // 0..127
            int p = (rest >> 5) * 64 + nh * 32 + (rest & 31);   // phys B row
            gload_lds16(gB + (size_t)p * K + k0 + tgr * 8,
                        &lds[dbuf][1][(nh * 128 + g * 64) * BK + th * 8]);
        }
    };

    auto ldA = [&](const bf16s* base, int mh, int mp, int kk) -> bf16x8 {
        int l = mh * 128 + wm * 64 + mp * 16 + lr;
        int c = ((kk << 2) | kg) ^ (lr & 7);
        return *(const bf16x8*)(base + l * BK + c * 8);
    };
    auto ldB = [&](const bf16s* base, int nh, int np, int kk) -> bf16x8 {
        int l = nh * 128 + wn * 32 + np * 16 + lr;
        int c = ((kk << 2) | kg) ^ (lr & 7);
        return *(const bf16x8*)(base + l * BK + c * 8);
    };

    bf16x8 a0[4][2], a1[4][2], b0[2][2], b1[2][2];

    auto readA = [&](bf16x8 (&dst)[4][2], const bf16s* base, int mh) {
#pragma unroll
        for (int mp = 0; mp < 4; ++mp)
#pragma unroll
            for (int kk = 0; kk < 2; ++kk)
                dst[mp][kk] = ldA(base, mh, mp, kk);
    };
    auto readB = [&](bf16x8 (&dst)[2][2], const bf16s* base, int nh) {
#pragma unroll
        for (int np = 0; np < 2; ++np)
#pragma unroll
            for (int kk = 0; kk < 2; ++kk)
                dst[np][kk] = ldB(base, nh, np, kk);
    };
    auto mfma16 = [&](int mo, int no, bf16x8 (&a)[4][2], bf16x8 (&b)[2][2]) {
        __builtin_amdgcn_s_setprio(1);
#pragma unroll
        for (int mp = 0; mp < 4; ++mp)
#pragma unroll
            for (int np = 0; np < 2; ++np)
#pragma unroll
                for (int kk = 0; kk < 2; ++kk)
                    acc[mo + mp][no + np] = __builtin_amdgcn_mfma_f32_16x16x32_bf16(
                        a[mp][kk], b[np][kk], acc[mo + mp][no + np], 0, 0, 0);
        __builtin_amdgcn_s_setprio(0);
    };

    // template-exact phase fencing helpers
#define PRE_MFMA_BAR()                                   \
    __builtin_amdgcn_s_barrier();                        \
    asm volatile("s_waitcnt lgkmcnt(0)");                \
    __builtin_amdgcn_sched_barrier(0)
#define POST_MFMA_BAR() __builtin_amdgcn_s_barrier()

    const bf16s* Ab0 = &lds[0][0][0];
    const bf16s* Bb0 = &lds[0][1][0];
    const bf16s* Ab1 = &lds[1][0][0];
    const bf16s* Bb1 = &lds[1][1][0];

    // ---- prologue: tile0 (4 halves) + tile1 (3 halves); retire tile0 ----
    stageA(0, 0, 0); stageB(0, 0, 0); stageB(0, 1, 0); stageA(0, 1, 0);
    stageA(1, 0, BK); stageB(1, 0, BK); stageB(1, 1, BK);
    asm volatile("s_waitcnt vmcnt(6)" ::: "memory");
    __builtin_amdgcn_s_barrier();

    for (int it = 0; it < NIT; ++it) {
        const int u   = 2 * it;
        const int kv  = (u + 1) * BK;
        const int ku2 = ((u + 2) < NT ? (u + 2) : (NT - 1)) * BK;   // clamped tail
        const int kv2 = ((u + 3) < NT ? (u + 3) : (NT - 1)) * BK;

        // ---- ph1: tile u, quad(mh0,nh0); stage A1(v) ----
        readA(a0, Ab0, 0); readB(b0, Bb0, 0);            // 12 ds_reads
        stageA(1, 1, kv);
        asm volatile("s_waitcnt lgkmcnt(8)");
        PRE_MFMA_BAR();
        mfma16(0, 0, a0, b0);
        POST_MFMA_BAR();

        // ---- ph2: quad(mh0,nh1); stage A0(u+2) ----
        readB(b1, Bb0, 1);                               // 4 ds_reads
        stageA(0, 0, ku2);
        PRE_MFMA_BAR();
        mfma16(0, 2, a0, b1);
        POST_MFMA_BAR();

        // ---- ph3: quad(mh1,nh1); stage B0(u+2) ----
        readA(a1, Ab0, 1);                               // 8 ds_reads
        stageB(0, 0, ku2);
        PRE_MFMA_BAR();
        mfma16(4, 2, a1, b1);
        POST_MFMA_BAR();

        // ---- ph4: quad(mh1,nh0); stage B1(u+2); WAIT -> tile v landed ----
        stageB(0, 1, ku2);
        PRE_MFMA_BAR();
        mfma16(4, 0, a1, b0);
        asm volatile("s_waitcnt vmcnt(6)" ::: "memory");
        __builtin_amdgcn_s_barrier();

        // ---- ph5: tile v, quad(mh0,nh0); stage A1(u+2) ----
        readA(a0, Ab1, 0); readB(b0, Bb1, 0);            // 12 ds_reads
        stageA(0, 1, ku2);
        asm volatile("s_waitcnt lgkmcnt(8)");
        PRE_MFMA_BAR();
        mfma16(0, 0, a0, b0);
        POST_MFMA_BAR();

        // ---- ph6: quad(mh0,nh1); stage A0(v+2) ----
        readB(b1, Bb1, 1);
        stageA(1, 0, kv2);
        PRE_MFMA_BAR();
        mfma16(0, 2, a0, b1);
        POST_MFMA_BAR();

        // ---- ph7: quad(mh1,nh1); stage B0(v+2) ----
        readA(a1, Ab1, 1);
        stageB(1, 0, kv2);
        PRE_MFMA_BAR();
        mfma16(4, 2, a1, b1);
        POST_MFMA_BAR();

        // ---- ph8: quad(mh1,nh0); stage B1(v+2); WAIT -> tile u+2 landed ----
        stageB(1, 1, kv2);
        PRE_MFMA_BAR();
        mfma16(4, 0, a1, b0);
        asm volatile("s_waitcnt vmcnt(6)" ::: "memory");
        __builtin_amdgcn_s_barrier();
    }
#undef PRE_MFMA_BAR
#undef POST_MFMA_BAR

    // drain remaining LDS-DMA before s_endpgm
    asm volatile("s_waitcnt vmcnt(0)" ::: "memory");

    // ---- epilogue: C/D layout col = lane&15, row = (lane>>4)*4 + q ----
    const int crow = bm * BM + wm * 128;
    const int ccol = bn * BN + wn * 64;
#pragma unroll
    for (int n = 0; n < 4; ++n) {
        int col = ccol + n * 16 + lr;
        float bv = bias[col];
#pragma unroll
        for (int m = 0; m < 8; ++m) {
            int row0 = crow + m * 16 + kg * 4;
#pragma unroll
            for (int q = 0; q < 4; ++q)
                C[(size_t)(row0 + q) * N + col] = acc[m][n][q] + bv;
        }
    }
}

// ---------- fallback (f32, slow but correct) ----------
__global__ void xa_kernel(const float* __restrict__ x, const float* __restrict__ lA,
                          float* __restrict__ xa, long M, int K, int r) {
    long idx = (long)blockIdx.x * blockDim.x + threadIdx.x;
    long total = M * r;
    if (idx >= total) return;
    long m = idx / r; int j = (int)(idx % r);
    const float* xr = x + m * (long)K;
    const float* ar = lA + (size_t)j * K;
    float s = 0.f;
    for (int k = 0; k < K; k += 4) {
        float4 xv = *(const float4*)&xr[k];
        float4 av = *(const float4*)&ar[k];
        s += xv.x * av.x + xv.y * av.y + xv.z * av.z + xv.w * av.w;
    }
    xa[idx] = s;
}

__global__ void naive_out(const float* __restrict__ x, const float* __restrict__ W,
                          const float* __restrict__ bias, const float* __restrict__ xa,
                          const float* __restrict__ lB, float* __restrict__ out,
                          long M, int N, int K, int r) {
    long idx = (long)blockIdx.x * blockDim.x + threadIdx.x;
    long total = M * (long)N;
    if (idx >= total) return;
    long m = idx / N; int n = (int)(idx % N);
    const float* xr = x + m * (long)K;
    const float* wr = W + (size_t)n * K;
    float s = bias[n];
    for (int k = 0; k < K; k += 4) {
        float4 xv = *(const float4*)&xr[k];
        float4 wv = *(const float4*)&wr[k];
        s += xv.x * wv.x + xv.y * wv.y + xv.z * wv.z + xv.w * wv.w;
    }
    const float* xar = xa + m * r;
    const float* br  = lB + (size_t)n * r;
    for (int j = 0; j < r; ++j) s += xar[j] * br[j];
    out[idx] = s;
}

extern "C" void kernel_launch(void* const* d_in, const int* in_sizes, int n_in,
                              void* d_out, int out_size, void* d_ws, size_t ws_size,
                              hipStream_t stream) {
    const float* x    = (const float*)d_in[0];
    const float* W    = (const float*)d_in[1];
    const float* bias = (const float*)d_in[2];
    const float* lA   = (const float*)d_in[3];
    const float* lB   = (const float*)d_in[4];
    float* out = (float*)d_out;

    const int  N  = in_sizes[2];                  // d_out = 4096
    const int  Kd = in_sizes[1] / N;              // d_in  = 4096
    const int  r  = in_sizes[4] / N;              // 16
    const long M  = (long)in_sizes[0] / Kd;       // B*S   = 8192

    size_t xb_bytes = (size_t)M * Kd * sizeof(bf16s);
    size_t wb_bytes = (size_t)N * Kd * sizeof(bf16s);

    const int NTv = Kd / BK;
    if (ws_size >= xb_bytes + wb_bytes &&
        (M % BM) == 0 && (N % BN) == 0 && (Kd % BK) == 0 &&
        NTv >= 4 && (NTv % 2) == 0) {
        bf16s* xb = (bf16s*)d_ws;
        bf16s* wb = (bf16s*)((char*)d_ws + xb_bytes);

        long n4 = (long)M * Kd / 4;
        long total_w = (long)N * (Kd / 4);
        int blk_w = (int)((total_w + 255) / 256);
        prep_fused<<<XBLK + blk_w, 256, 0, stream>>>(x, xb, n4, W, lA, lB, wb, N, Kd, r);

        int grid = (int)(M / BM) * (N / BN);
        gemm_m201f<<<grid, 512, 0, stream>>>(xb, wb, bias, out, (int)M, N, Kd);
    } else {
        // f32 fallback: xa = x @ lA^T  (M x r), then naive out
        float* xa = (float*)d_ws;   // needs M*r*4 bytes = 512 KB
        long total_xa = M * (long)r;
        int blk_xa = (int)((total_xa + 255) / 256);
        xa_kernel<<<blk_xa, 256, 0, stream>>>(x, lA, xa, M, Kd, r);
        long total_o = M * (long)N;
        int blk_o = (int)((total_o + 255) / 256);
        naive_out<<<blk_o, 256, 0, stream>>>(x, W, bias, xa, lB, out, M, N, Kd, r);
    }
}

// Round 13
// 309.766 us; speedup vs baseline: 1.4667x; 1.0164x over previous
//
#include <hip/hip_runtime.h>
#include <hip/hip_bf16.h>
#include <stdint.h>

typedef __hip_bfloat16 bf16s;                                    // storage type
typedef __bf16 bf16x8 __attribute__((ext_vector_type(8)));       // MFMA operand
typedef float  floatx4 __attribute__((ext_vector_type(4)));      // MFMA acc

#define BM 256
#define BN 256
#define BK 64

__device__ __forceinline__ void gload_lds16(const void* g, void* l) {
    auto* gp = reinterpret_cast<const __attribute__((address_space(1))) uint32_t*>(
        reinterpret_cast<uintptr_t>(g));
    auto* lp = reinterpret_cast<__attribute__((address_space(3))) uint32_t*>(
        reinterpret_cast<uintptr_t>(l));
    __builtin_amdgcn_global_load_lds(gp, lp, 16, 0, 0);
}

// ---------- fused: x (f32)->bf16  +  Wadj = W + lora_B@lora_A -> bf16 ----------
#define XBLK 2048
__global__ void prep_fused(const float* __restrict__ x, bf16s* __restrict__ xb, long n4,
                           const float* __restrict__ W, const float* __restrict__ lA,
                           const float* __restrict__ lB, bf16s* __restrict__ wb,
                           int N, int Kd, int r) {
    if (blockIdx.x < XBLK) {
        long i = (long)blockIdx.x * blockDim.x + threadIdx.x;
        long stride = (long)XBLK * blockDim.x;
        for (; i < n4; i += stride) {
            float4 v = ((const float4*)x)[i];
            bf16s tmp[4];
            tmp[0] = __float2bfloat16(v.x);
            tmp[1] = __float2bfloat16(v.y);
            tmp[2] = __float2bfloat16(v.z);
            tmp[3] = __float2bfloat16(v.w);
            *(uint2*)&xb[i * 4] = *(uint2*)tmp;
        }
    } else {
        long idx = (long)(blockIdx.x - XBLK) * blockDim.x + threadIdx.x;
        int kq = Kd >> 2;
        long total = (long)N * kq;
        if (idx >= total) return;
        int n  = (int)(idx / kq);
        int k4 = (int)(idx - (long)n * kq) << 2;
        float4 w = *(const float4*)&W[(size_t)n * Kd + k4];
        float a0 = w.x, a1 = w.y, a2 = w.z, a3 = w.w;
        for (int j = 0; j < r; ++j) {
            float b = lB[n * r + j];
            float4 av = *(const float4*)&lA[(size_t)j * Kd + k4];
            a0 += b * av.x; a1 += b * av.y; a2 += b * av.z; a3 += b * av.w;
        }
        bf16s tmp[4];
        tmp[0] = __float2bfloat16(a0);
        tmp[1] = __float2bfloat16(a1);
        tmp[2] = __float2bfloat16(a2);
        tmp[3] = __float2bfloat16(a3);
        *(uint2*)&wb[(size_t)n * Kd + k4] = *(uint2*)tmp;
    }
}

// ==========================================================================
// r12 (m201 cadence + template fencing) with WAR-FREE QUADRANT ORDER:
//   per tile: q00(rd a0,b0) -> q01(rd b1) -> q10(rd a1) -> q11(rd none)
// Operand-set lifetime proof (steady state, per 4-phase tile):
//   a0: read P1,P2, written P5 (sep 3)   b0: read P1,P3, written P5 (sep 2)
//   b1: read P2,P4, written P6 (sep 2)   a1: read P3,P4, written P7 (sep 3)
// => every ds_read destination was last consumed >=2 phases (>=1200cy) ago,
// so next-phase reads never WAR-stall behind the in-flight MFMA drain
// (~620cy/SIMD). r9/r12's order (q11 before q10) wrote b0 one phase after
// its last MFMA reader every tile — hypothesized cause of the pinned 46%.
// Staging order / vmcnt(6)@P4,P8 ledger / swizzle / epilogue: identical r12.
// ==========================================================================
__global__ __launch_bounds__(512, 2)
void gemm_war0(const bf16s* __restrict__ A,   // [M,K] bf16
               const bf16s* __restrict__ B,   // [N,K] bf16
               const float* __restrict__ bias,
               float* __restrict__ C,         // [M,N] f32
               int M, int N, int K) {
    __shared__ __align__(16) bf16s lds[2][2][BM * BK];   // [dbuf][A=0/B=1] 128 KiB

    const int nbn = N / BN;
    const int nwg = gridDim.x;
    int bid = blockIdx.x;
    int swz = bid;
    if ((nwg & 7) == 0) swz = (bid & 7) * (nwg >> 3) + (bid >> 3);   // XCD swizzle
    const int bm = swz / nbn, bn = swz % nbn;

    const int th   = threadIdx.x;
    const int lane = th & 63;
    const int wid  = th >> 6;
    const int wm = wid >> 2;           // 0..1 -> 128-row slice
    const int wn = wid & 3;            // 0..3 -> 64-col slice
    const int lr = lane & 15;
    const int kg = lane >> 4;          // 16B granule group along K

    const bf16s* gA = A + (size_t)(bm * BM) * K;
    const bf16s* gB = B + (size_t)(bn * BN) * K;
    const int NT  = K / BK;            // 64
    const int NIT = NT / 2;            // 32

    floatx4 acc[8][4];
#pragma unroll
    for (int m = 0; m < 8; ++m)
#pragma unroll
        for (int n = 0; n < 4; ++n)
            acc[m][n] = (floatx4){0.f, 0.f, 0.f, 0.f};

    const int trow = th >> 3;                       // 0..63 rows per G-load
    const int tgr  = (th & 7) ^ (trow & 7);         // pre-swizzled src granule

    auto stageA = [&](int dbuf, int mh, int k0) {
#pragma unroll
        for (int g = 0; g < 2; ++g) {
            int p = g * 128 + mh * 64 + trow;       // phys A row
            gload_lds16(gA + (size_t)p * K + k0 + tgr * 8,
                        &lds[dbuf][0][(mh * 128 + g * 64) * BK + th * 8]);
        }
    };
    auto stageB = [&](int dbuf, int nh, int k0) {
#pragma unroll
        for (int g = 0; g < 2; ++g) {
            int rest = g * 64 + trow;               // 0..127
            int p = (rest >> 5) * 64 + nh * 32 + (rest & 31);   // phys B row
            gload_lds16(gB + (size_t)p * K + k0 + tgr * 8,
                        &lds[dbuf][1][(nh * 128 + g * 64) * BK + th * 8]);
        }
    };

    auto ldA = [&](const bf16s* base, int mh, int mp, int kk) -> bf16x8 {
        int l = mh * 128 + wm * 64 + mp * 16 + lr;
        int c = ((kk << 2) | kg) ^ (lr & 7);
        return *(const bf16x8*)(base + l * BK + c * 8);
    };
    auto ldB = [&](const bf16s* base, int nh, int np, int kk) -> bf16x8 {
        int l = nh * 128 + wn * 32 + np * 16 + lr;
        int c = ((kk << 2) | kg) ^ (lr & 7);
        return *(const bf16x8*)(base + l * BK + c * 8);
    };

    bf16x8 a0[4][2], a1[4][2], b0[2][2], b1[2][2];

    auto readA = [&](bf16x8 (&dst)[4][2], const bf16s* base, int mh) {
#pragma unroll
        for (int mp = 0; mp < 4; ++mp)
#pragma unroll
            for (int kk = 0; kk < 2; ++kk)
                dst[mp][kk] = ldA(base, mh, mp, kk);
    };
    auto readB = [&](bf16x8 (&dst)[2][2], const bf16s* base, int nh) {
#pragma unroll
        for (int np = 0; np < 2; ++np)
#pragma unroll
            for (int kk = 0; kk < 2; ++kk)
                dst[np][kk] = ldB(base, nh, np, kk);
    };
    auto mfma16 = [&](int mo, int no, bf16x8 (&a)[4][2], bf16x8 (&b)[2][2]) {
        __builtin_amdgcn_s_setprio(1);
#pragma unroll
        for (int mp = 0; mp < 4; ++mp)
#pragma unroll
            for (int np = 0; np < 2; ++np)
#pragma unroll
                for (int kk = 0; kk < 2; ++kk)
                    acc[mo + mp][no + np] = __builtin_amdgcn_mfma_f32_16x16x32_bf16(
                        a[mp][kk], b[np][kk], acc[mo + mp][no + np], 0, 0, 0);
        __builtin_amdgcn_s_setprio(0);
    };

#define PRE_MFMA_BAR()                                   \
    __builtin_amdgcn_s_barrier();                        \
    asm volatile("s_waitcnt lgkmcnt(0)");                \
    __builtin_amdgcn_sched_barrier(0)
#define POST_MFMA_BAR() __builtin_amdgcn_s_barrier()

    const bf16s* Ab0 = &lds[0][0][0];
    const bf16s* Bb0 = &lds[0][1][0];
    const bf16s* Ab1 = &lds[1][0][0];
    const bf16s* Bb1 = &lds[1][1][0];

    // ---- prologue: tile0 (4 halves) + tile1 (3 halves); retire tile0 ----
    stageA(0, 0, 0); stageB(0, 0, 0); stageB(0, 1, 0); stageA(0, 1, 0);
    stageA(1, 0, BK); stageB(1, 0, BK); stageB(1, 1, BK);
    asm volatile("s_waitcnt vmcnt(6)" ::: "memory");
    __builtin_amdgcn_s_barrier();

    for (int it = 0; it < NIT; ++it) {
        const int u   = 2 * it;
        const int kv  = (u + 1) * BK;
        const int ku2 = ((u + 2) < NT ? (u + 2) : (NT - 1)) * BK;   // clamped tail
        const int kv2 = ((u + 3) < NT ? (u + 3) : (NT - 1)) * BK;

        // ---- ph1: tile u, q00; stage A1(v) ----
        readA(a0, Ab0, 0); readB(b0, Bb0, 0);            // 12 ds_reads
        stageA(1, 1, kv);
        asm volatile("s_waitcnt lgkmcnt(8)");
        PRE_MFMA_BAR();
        mfma16(0, 0, a0, b0);
        POST_MFMA_BAR();

        // ---- ph2: q01; stage A0(u+2) ----
        readB(b1, Bb0, 1);                               // 4 ds_reads
        stageA(0, 0, ku2);
        PRE_MFMA_BAR();
        mfma16(0, 2, a0, b1);
        POST_MFMA_BAR();

        // ---- ph3: q10; stage B0(u+2) ----
        readA(a1, Ab0, 1);                               // 8 ds_reads
        stageB(0, 0, ku2);
        PRE_MFMA_BAR();
        mfma16(4, 0, a1, b0);
        POST_MFMA_BAR();

        // ---- ph4: q11; stage B1(u+2); WAIT -> tile v landed ----
        stageB(0, 1, ku2);
        PRE_MFMA_BAR();
        mfma16(4, 2, a1, b1);
        asm volatile("s_waitcnt vmcnt(6)" ::: "memory");
        __builtin_amdgcn_s_barrier();

        // ---- ph5: tile v, q00; stage A1(u+2) ----
        readA(a0, Ab1, 0); readB(b0, Bb1, 0);            // 12 ds_reads
        stageA(0, 1, ku2);
        asm volatile("s_waitcnt lgkmcnt(8)");
        PRE_MFMA_BAR();
        mfma16(0, 0, a0, b0);
        POST_MFMA_BAR();

        // ---- ph6: q01; stage A0(v+2) ----
        readB(b1, Bb1, 1);
        stageA(1, 0, kv2);
        PRE_MFMA_BAR();
        mfma16(0, 2, a0, b1);
        POST_MFMA_BAR();

        // ---- ph7: q10; stage B0(v+2) ----
        readA(a1, Ab1, 1);
        stageB(1, 0, kv2);
        PRE_MFMA_BAR();
        mfma16(4, 0, a1, b0);
        POST_MFMA_BAR();

        // ---- ph8: q11; stage B1(v+2); WAIT -> tile u+2 landed ----
        stageB(1, 1, kv2);
        PRE_MFMA_BAR();
        mfma16(4, 2, a1, b1);
        asm volatile("s_waitcnt vmcnt(6)" ::: "memory");
        __builtin_amdgcn_s_barrier();
    }
#undef PRE_MFMA_BAR
#undef POST_MFMA_BAR

    // drain remaining LDS-DMA before s_endpgm
    asm volatile("s_waitcnt vmcnt(0)" ::: "memory");

    // ---- epilogue: C/D layout col = lane&15, row = (lane>>4)*4 + q ----
    const int crow = bm * BM + wm * 128;
    const int ccol = bn * BN + wn * 64;
#pragma unroll
    for (int n = 0; n < 4; ++n) {
        int col = ccol + n * 16 + lr;
        float bv = bias[col];
#pragma unroll
        for (int m = 0; m < 8; ++m) {
            int row0 = crow + m * 16 + kg * 4;
#pragma unroll
            for (int q = 0; q < 4; ++q)
                C[(size_t)(row0 + q) * N + col] = acc[m][n][q] + bv;
        }
    }
}

// ---------- fallback (f32, slow but correct) ----------
__global__ void xa_kernel(const float* __restrict__ x, const float* __restrict__ lA,
                          float* __restrict__ xa, long M, int K, int r) {
    long idx = (long)blockIdx.x * blockDim.x + threadIdx.x;
    long total = M * r;
    if (idx >= total) return;
    long m = idx / r; int j = (int)(idx % r);
    const float* xr = x + m * (long)K;
    const float* ar = lA + (size_t)j * K;
    float s = 0.f;
    for (int k = 0; k < K; k += 4) {
        float4 xv = *(const float4*)&xr[k];
        float4 av = *(const float4*)&ar[k];
        s += xv.x * av.x + xv.y * av.y + xv.z * av.z + xv.w * av.w;
    }
    xa[idx] = s;
}

__global__ void naive_out(const float* __restrict__ x, const float* __restrict__ W,
                          const float* __restrict__ bias, const float* __restrict__ xa,
                          const float* __restrict__ lB, float* __restrict__ out,
                          long M, int N, int K, int r) {
    long idx = (long)blockIdx.x * blockDim.x + threadIdx.x;
    long total = M * (long)N;
    if (idx >= total) return;
    long m = idx / N; int n = (int)(idx % N);
    const float* xr = x + m * (long)K;
    const float* wr = W + (size_t)n * K;
    float s = bias[n];
    for (int k = 0; k < K; k += 4) {
        float4 xv = *(const float4*)&xr[k];
        float4 wv = *(const float4*)&wr[k];
        s += xv.x * wv.x + xv.y * wv.y + xv.z * wv.z + xv.w * wv.w;
    }
    const float* xar = xa + m * r;
    const float* br  = lB + (size_t)n * r;
    for (int j = 0; j < r; ++j) s += xar[j] * br[j];
    out[idx] = s;
}

extern "C" void kernel_launch(void* const* d_in, const int* in_sizes, int n_in,
                              void* d_out, int out_size, void* d_ws, size_t ws_size,
                              hipStream_t stream) {
    const float* x    = (const float*)d_in[0];
    const float* W    = (const float*)d_in[1];
    const float* bias = (const float*)d_in[2];
    const float* lA   = (const float*)d_in[3];
    const float* lB   = (const float*)d_in[4];
    float* out = (float*)d_out;

    const int  N  = in_sizes[2];                  // d_out = 4096
    const int  Kd = in_sizes[1] / N;              // d_in  = 4096
    const int  r  = in_sizes[4] / N;              // 16
    const long M  = (long)in_sizes[0] / Kd;       // B*S   = 8192

    size_t xb_bytes = (size_t)M * Kd * sizeof(bf16s);
    size_t wb_bytes = (size_t)N * Kd * sizeof(bf16s);

    const int NTv = Kd / BK;
    if (ws_size >= xb_bytes + wb_bytes &&
        (M % BM) == 0 && (N % BN) == 0 && (Kd % BK) == 0 &&
        NTv >= 4 && (NTv % 2) == 0) {
        bf16s* xb = (bf16s*)d_ws;
        bf16s* wb = (bf16s*)((char*)d_ws + xb_bytes);

        long n4 = (long)M * Kd / 4;
        long total_w = (long)N * (Kd / 4);
        int blk_w = (int)((total_w + 255) / 256);
        prep_fused<<<XBLK + blk_w, 256, 0, stream>>>(x, xb, n4, W, lA, lB, wb, N, Kd, r);

        int grid = (int)(M / BM) * (N / BN);
        gemm_war0<<<grid, 512, 0, stream>>>(xb, wb, bias, out, (int)M, N, Kd);
    } else {
        // f32 fallback: xa = x @ lA^T  (M x r), then naive out
        float* xa = (float*)d_ws;   // needs M*r*4 bytes = 512 KB
        long total_xa = M * (long)r;
        int blk_xa = (int)((total_xa + 255) / 256);
        xa_kernel<<<blk_xa, 256, 0, stream>>>(x, lA, xa, M, Kd, r);
        long total_o = M * (long)N;
        int blk_o = (int)((total_o + 255) / 256);
        naive_out<<<blk_o, 256, 0, stream>>>(x, W, bias, xa, lB, out, M, N, Kd, r);
    }
}

// Round 15
// 212.266 us; speedup vs baseline: 2.1404x; 1.4593x over previous
//
#include <hip/hip_runtime.h>
#include <hip/hip_bf16.h>
#include <stdint.h>

typedef int   intx4  __attribute__((ext_vector_type(4)));   // i8 MFMA operand / i32 acc
typedef float floatx4 __attribute__((ext_vector_type(4)));

#define BM  256
#define BN  256
#define BKB 128        // K-bytes (= i8 elems) per tile

__device__ __forceinline__ void gload_lds16(const void* g, void* l) {
    auto* gp = reinterpret_cast<const __attribute__((address_space(1))) uint32_t*>(
        reinterpret_cast<uintptr_t>(g));
    auto* lp = reinterpret_cast<__attribute__((address_space(3))) uint32_t*>(
        reinterpret_cast<uintptr_t>(l));
    __builtin_amdgcn_global_load_lds(gp, lp, 16, 0, 0);
}

// ==========================================================================
// Fused per-row quantizer (unchanged from r14 — produced absmax 0.094):
// blocks [0,M) quantize x rows; [M,M+N) compute Wadj rows and quantize.
// ==========================================================================
__global__ void quant_fused(const float* __restrict__ x, const float* __restrict__ W,
                            const float* __restrict__ lA, const float* __restrict__ lB,
                            int8_t* __restrict__ xq, int8_t* __restrict__ wq,
                            float* __restrict__ sx, float* __restrict__ sw,
                            long Mrows, int N, int K, int r) {
    __shared__ float rowbuf[4096];
    __shared__ float red[4];
    const int tid = threadIdx.x;
    const long b = blockIdx.x;
    const bool isW = (b >= Mrows);
    const long row = isW ? (b - Mrows) : b;
    const int nchunk = K >> 10;                 // K/(256*4)

    float am = 0.f;
    if (!isW) {
        const float* xr = x + (size_t)row * K;
        for (int i = 0; i < nchunk; ++i) {
            float4 f = ((const float4*)xr)[i * 256 + tid];
            ((float4*)rowbuf)[i * 256 + tid] = f;
            am = fmaxf(am, fmaxf(fmaxf(fabsf(f.x), fabsf(f.y)),
                                 fmaxf(fabsf(f.z), fabsf(f.w))));
        }
    } else {
        const float* wr = W + (size_t)row * K;
        for (int i = 0; i < nchunk; ++i) {
            float4 f = ((const float4*)wr)[i * 256 + tid];
            for (int j = 0; j < r; ++j) {
                float bj = lB[row * r + j];
                float4 a = ((const float4*)(lA + (size_t)j * K))[i * 256 + tid];
                f.x += bj * a.x; f.y += bj * a.y; f.z += bj * a.z; f.w += bj * a.w;
            }
            ((float4*)rowbuf)[i * 256 + tid] = f;
            am = fmaxf(am, fmaxf(fmaxf(fabsf(f.x), fabsf(f.y)),
                                 fmaxf(fabsf(f.z), fabsf(f.w))));
        }
    }
#pragma unroll
    for (int off = 32; off; off >>= 1) am = fmaxf(am, __shfl_xor(am, off));
    if ((tid & 63) == 0) red[tid >> 6] = am;
    __syncthreads();
    am = fmaxf(fmaxf(red[0], red[1]), fmaxf(red[2], red[3]));
    const float inv = am > 0.f ? 127.0f / am : 0.f;
    if (tid == 0) {
        if (isW) sw[row] = am > 0.f ? am / 127.0f : 0.f;
        else     sx[row] = am > 0.f ? am / 127.0f : 0.f;
    }
    int8_t* dst = isW ? (wq + (size_t)row * K) : (xq + (size_t)row * K);
    for (int i = 0; i < nchunk; ++i) {
        float4 f = ((const float4*)rowbuf)[i * 256 + tid];
        int q0 = min(127, max(-127, (int)rintf(f.x * inv)));
        int q1 = min(127, max(-127, (int)rintf(f.y * inv)));
        int q2 = min(127, max(-127, (int)rintf(f.z * inv)));
        int q3 = min(127, max(-127, (int)rintf(f.w * inv)));
        int packed = (q0 & 255) | ((q1 & 255) << 8) | ((q2 & 255) << 16) | (q3 << 24);
        *(int*)(dst + ((size_t)(i * 256 + tid)) * 4) = packed;
    }
}

// ==========================================================================
// i8 GEMM with the r7 FULL-DRAIN sync structure (race-minimal; r7 passed
// post-timing in bf16). One boundary per K-tile: vmcnt(0)+barrier — zero
// DMAs in flight across any barrier, so no counted-wait ledger to get wrong.
// r14's counted-vmcnt i8 version diverged post-timing (1.42 stale-tile
// signature); this removes that hazard class at a measured-in-bf16 cost of
// ~1% (r7 268 vs r9 265 us).
// Per K-tile (K=128 i8): stage t+1 (8 gload_lds, non-current buf only) |
// read 24 frags | 64 mfma_i32_16x16x64_i8 | vmcnt(0)+barrier.
// Swizzle/staging byte-identical to r14 (correct pre-timing, 0 conflicts):
// LDS slot s of row l holds source granule s^(l&7).
// Epilogue rescales i32 acc by sx[row]*sw[col] (C/D layout dtype-indep).
// ==========================================================================
__global__ __launch_bounds__(512, 2)
void gemm_i8d(const int8_t* __restrict__ A,   // [M,K] i8, per-row scale sx
              const int8_t* __restrict__ B,   // [N,K] i8, per-row scale sw
              const float* __restrict__ bias,
              const float* __restrict__ sx, const float* __restrict__ sw,
              float* __restrict__ C,          // [M,N] f32
              int M, int N, int K) {
    __shared__ __align__(16) int8_t lds[2][2][BM * BKB];   // 128 KiB

    const int nbn = N / BN;
    const int nwg = gridDim.x;
    int bid = blockIdx.x;
    int swz = bid;
    if ((nwg & 7) == 0) swz = (bid & 7) * (nwg >> 3) + (bid >> 3);   // XCD swizzle
    const int bm = swz / nbn, bn = swz % nbn;

    const int th   = threadIdx.x;
    const int lane = th & 63;
    const int wid  = th >> 6;
    const int wm = wid >> 2;           // 0..1 -> 128-row slice
    const int wn = wid & 3;            // 0..3 -> 64-col slice
    const int lr = lane & 15;
    const int kg = lane >> 4;          // 16B granule group along K

    const int8_t* gA = A + (size_t)(bm * BM) * K;
    const int8_t* gB = B + (size_t)(bn * BN) * K;
    const int NT = K / BKB;            // 32

    intx4 acc[8][4];
#pragma unroll
    for (int m = 0; m < 8; ++m)
#pragma unroll
        for (int n = 0; n < 4; ++n)
            acc[m][n] = (intx4){0, 0, 0, 0};

    const int trow = th >> 3;                       // 0..63 rows per G-load
    const int tgr  = (th & 7) ^ (trow & 7);         // pre-swizzled src granule

    auto stageA = [&](int dbuf, int mh, int k0) {
#pragma unroll
        for (int g = 0; g < 2; ++g) {
            int p = g * 128 + mh * 64 + trow;       // phys A row
            gload_lds16(gA + (size_t)p * K + k0 + tgr * 16,
                        &lds[dbuf][0][(mh * 128 + g * 64) * BKB + th * 16]);
        }
    };
    auto stageB = [&](int dbuf, int nh, int k0) {
#pragma unroll
        for (int g = 0; g < 2; ++g) {
            int rest = g * 64 + trow;               // 0..127
            int p = (rest >> 5) * 64 + nh * 32 + (rest & 31);   // phys B row
            gload_lds16(gB + (size_t)p * K + k0 + tgr * 16,
                        &lds[dbuf][1][(nh * 128 + g * 64) * BKB + th * 16]);
        }
    };

    auto ldA = [&](const int8_t* base, int mh, int mp, int kk) -> intx4 {
        int l = mh * 128 + wm * 64 + mp * 16 + lr;
        int c = ((kk << 2) | kg) ^ (lr & 7);
        return *(const intx4*)(base + l * BKB + c * 16);
    };
    auto ldB = [&](const int8_t* base, int nh, int np, int kk) -> intx4 {
        int l = nh * 128 + wn * 32 + np * 16 + lr;
        int c = ((kk << 2) | kg) ^ (lr & 7);
        return *(const intx4*)(base + l * BKB + c * 16);
    };

    // ---- prologue: stage tile 0, publish (full drain) ----
    stageA(0, 0, 0); stageB(0, 0, 0); stageB(0, 1, 0); stageA(0, 1, 0);
    asm volatile("s_waitcnt vmcnt(0)" ::: "memory");
    asm volatile("s_barrier" ::: "memory");

    for (int t = 0; t < NT; ++t) {
        const int8_t* Ab = &lds[t & 1][0][0];
        const int8_t* Bb = &lds[t & 1][1][0];
        const int nb = (t + 1) & 1;

        // stage t+1 into the non-current buffer (readers of it all passed
        // the previous boundary; no DMA outstanding from before)
        if (t + 1 < NT) {
            const int k1 = (t + 1) * BKB;
            stageA(nb, 0, k1);
            stageB(nb, 0, k1);
            stageB(nb, 1, k1);
            stageA(nb, 1, k1);
        }

        // read all 24 fragments (compiler inserts fine lgkmcnt before MFMA)
        intx4 af[4][2], af2[4][2], b0[2][2], b1[2][2];
#pragma unroll
        for (int mp = 0; mp < 4; ++mp)
#pragma unroll
            for (int kk = 0; kk < 2; ++kk)
                af[mp][kk] = ldA(Ab, 0, mp, kk);
#pragma unroll
        for (int np = 0; np < 2; ++np)
#pragma unroll
            for (int kk = 0; kk < 2; ++kk)
                b0[np][kk] = ldB(Bb, 0, np, kk);
#pragma unroll
        for (int np = 0; np < 2; ++np)
#pragma unroll
            for (int kk = 0; kk < 2; ++kk)
                b1[np][kk] = ldB(Bb, 1, np, kk);
#pragma unroll
        for (int mp = 0; mp < 4; ++mp)
#pragma unroll
            for (int kk = 0; kk < 2; ++kk)
                af2[mp][kk] = ldA(Ab, 1, mp, kk);

        // 64 MFMA in 4 quadrant clusters
        __builtin_amdgcn_s_setprio(1);
#pragma unroll
        for (int mp = 0; mp < 4; ++mp)
#pragma unroll
            for (int np = 0; np < 2; ++np)
#pragma unroll
                for (int kk = 0; kk < 2; ++kk)
                    acc[mp][np] = __builtin_amdgcn_mfma_i32_16x16x64_i8(
                        af[mp][kk], b0[np][kk], acc[mp][np], 0, 0, 0);
#pragma unroll
        for (int mp = 0; mp < 4; ++mp)
#pragma unroll
            for (int np = 0; np < 2; ++np)
#pragma unroll
                for (int kk = 0; kk < 2; ++kk)
                    acc[mp][2 + np] = __builtin_amdgcn_mfma_i32_16x16x64_i8(
                        af[mp][kk], b1[np][kk], acc[mp][2 + np], 0, 0, 0);
#pragma unroll
        for (int mp = 0; mp < 4; ++mp)
#pragma unroll
            for (int np = 0; np < 2; ++np)
#pragma unroll
                for (int kk = 0; kk < 2; ++kk)
                    acc[4 + mp][np] = __builtin_amdgcn_mfma_i32_16x16x64_i8(
                        af2[mp][kk], b0[np][kk], acc[4 + mp][np], 0, 0, 0);
#pragma unroll
        for (int mp = 0; mp < 4; ++mp)
#pragma unroll
            for (int np = 0; np < 2; ++np)
#pragma unroll
                for (int kk = 0; kk < 2; ++kk)
                    acc[4 + mp][2 + np] = __builtin_amdgcn_mfma_i32_16x16x64_i8(
                        af2[mp][kk], b1[np][kk], acc[4 + mp][2 + np], 0, 0, 0);
        __builtin_amdgcn_s_setprio(0);

        // boundary: FULL drain — nothing in flight crosses the barrier
        asm volatile("s_waitcnt vmcnt(0)" ::: "memory");
        asm volatile("s_barrier" ::: "memory");
    }

    // ---- epilogue: C/D layout col = lane&15, row = (lane>>4)*4 + q ----
    const int crow = bm * BM + wm * 128;
    const int ccol = bn * BN + wn * 64;
#pragma unroll
    for (int n = 0; n < 4; ++n) {
        int col = ccol + n * 16 + lr;
        float bv  = bias[col];
        float swc = sw[col];
#pragma unroll
        for (int m = 0; m < 8; ++m) {
            int row0 = crow + m * 16 + kg * 4;
            float4 s4 = *(const float4*)&sx[row0];     // row0 % 4 == 0
            C[(size_t)(row0 + 0) * N + col] = (float)acc[m][n][0] * (s4.x * swc) + bv;
            C[(size_t)(row0 + 1) * N + col] = (float)acc[m][n][1] * (s4.y * swc) + bv;
            C[(size_t)(row0 + 2) * N + col] = (float)acc[m][n][2] * (s4.z * swc) + bv;
            C[(size_t)(row0 + 3) * N + col] = (float)acc[m][n][3] * (s4.w * swc) + bv;
        }
    }
}

// ---------- fallback (f32, slow but correct) ----------
__global__ void xa_kernel(const float* __restrict__ x, const float* __restrict__ lA,
                          float* __restrict__ xa, long M, int K, int r) {
    long idx = (long)blockIdx.x * blockDim.x + threadIdx.x;
    long total = M * r;
    if (idx >= total) return;
    long m = idx / r; int j = (int)(idx % r);
    const float* xr = x + m * (long)K;
    const float* ar = lA + (size_t)j * K;
    float s = 0.f;
    for (int k = 0; k < K; k += 4) {
        float4 xv = *(const float4*)&xr[k];
        float4 av = *(const float4*)&ar[k];
        s += xv.x * av.x + xv.y * av.y + xv.z * av.z + xv.w * av.w;
    }
    xa[idx] = s;
}

__global__ void naive_out(const float* __restrict__ x, const float* __restrict__ W,
                          const float* __restrict__ bias, const float* __restrict__ xa,
                          const float* __restrict__ lB, float* __restrict__ out,
                          long M, int N, int K, int r) {
    long idx = (long)blockIdx.x * blockDim.x + threadIdx.x;
    long total = M * (long)N;
    if (idx >= total) return;
    long m = idx / N; int n = (int)(idx % N);
    const float* xr = x + m * (long)K;
    const float* wr = W + (size_t)n * K;
    float s = bias[n];
    for (int k = 0; k < K; k += 4) {
        float4 xv = *(const float4*)&xr[k];
        float4 wv = *(const float4*)&wr[k];
        s += xv.x * wv.x + xv.y * wv.y + xv.z * wv.z + xv.w * wv.w;
    }
    const float* xar = xa + m * r;
    const float* br  = lB + (size_t)n * r;
    for (int j = 0; j < r; ++j) s += xar[j] * br[j];
    out[idx] = s;
}

extern "C" void kernel_launch(void* const* d_in, const int* in_sizes, int n_in,
                              void* d_out, int out_size, void* d_ws, size_t ws_size,
                              hipStream_t stream) {
    const float* x    = (const float*)d_in[0];
    const float* W    = (const float*)d_in[1];
    const float* bias = (const float*)d_in[2];
    const float* lA   = (const float*)d_in[3];
    const float* lB   = (const float*)d_in[4];
    float* out = (float*)d_out;

    const int  N  = in_sizes[2];                  // d_out = 4096
    const int  Kd = in_sizes[1] / N;              // d_in  = 4096
    const int  r  = in_sizes[4] / N;              // 16
    const long M  = (long)in_sizes[0] / Kd;       // B*S   = 8192

    size_t xq_bytes = (size_t)M * Kd;             // i8
    size_t wq_bytes = (size_t)N * Kd;             // i8
    size_t sx_bytes = (size_t)M * sizeof(float);
    size_t sw_bytes = (size_t)N * sizeof(float);

    if (ws_size >= xq_bytes + wq_bytes + sx_bytes + sw_bytes &&
        (M % BM) == 0 && (N % BN) == 0 &&
        (Kd % BKB) == 0 && (Kd % 1024) == 0 && Kd <= 4096 && (Kd / BKB) >= 2) {
        int8_t* xq = (int8_t*)d_ws;
        int8_t* wq = (int8_t*)d_ws + xq_bytes;
        float*  sx = (float*)((char*)d_ws + xq_bytes + wq_bytes);
        float*  sw = sx + M;

        quant_fused<<<(int)(M + N), 256, 0, stream>>>(x, W, lA, lB, xq, wq, sx, sw,
                                                      M, N, Kd, r);

        int grid = (int)(M / BM) * (N / BN);
        gemm_i8d<<<grid, 512, 0, stream>>>(xq, wq, bias, sx, sw, out, (int)M, N, Kd);
    } else {
        // f32 fallback: xa = x @ lA^T  (M x r), then naive out
        float* xa = (float*)d_ws;   // needs M*r*4 bytes = 512 KB
        long total_xa = M * (long)r;
        int blk_xa = (int)((total_xa + 255) / 256);
        xa_kernel<<<blk_xa, 256, 0, stream>>>(x, lA, xa, M, Kd, r);
        long total_o = M * (long)N;
        int blk_o = (int)((total_o + 255) / 256);
        naive_out<<<blk_o, 256, 0, stream>>>(x, W, bias, xa, lB, out, M, N, Kd, r);
    }
}